// Round 10
// baseline (97.801 us; speedup 1.0000x reference)
//
#include <hip/hip_runtime.h>
#include <hip/hip_bf16.h>
#include <stdint.h>

#define BATCH 4096
#define N_TOT 8192
#define D_DIM 256
#define SHIFT 150.0f
#define SQRT2 1.41421356237309515f
#define NWTILE 8256  // 128*129/2 triangular 64x64 wave-tiles
#define PLANE 8192   // rows per 16B k-chunk plane

typedef __bf16 bf16_t;
typedef bf16_t bf16x8 __attribute__((ext_vector_type(8)));
typedef bf16_t bf16x4 __attribute__((ext_vector_type(4)));
typedef float f32x4 __attribute__((ext_vector_type(4)));

#define VMCNT(N) asm volatile("s_waitcnt vmcnt(" #N ")" ::: "memory")
#define SCHED_FENCE() __builtin_amdgcn_sched_barrier(0)

// Fused: bf16 convert (x sqrt2) into PLANE-PACKED layout, positive-pair dot
// partials, Zrow zero-init. Packed layout: hbP element ((kc*8192 + row)*8 + e)
// holds original hb[row][kc*8 + e] -- so an MFMA fragment load (16 rows x one
// 16B k-chunk) is 16x16B CONTIGUOUS: perfectly coalesced straight from L2.
// 1024 blocks x 256 threads; wave w of block b owns row r = b*4+w.
__global__ void k_prep(const float* __restrict__ hi, const float* __restrict__ hj,
                       bf16_t* __restrict__ hbP, float* __restrict__ Zrow,
                       float* __restrict__ posPartial) {
  const int wave = threadIdx.x >> 6, lane = threadIdx.x & 63;
  const int r = blockIdx.x * 4 + wave;
  const size_t off = (size_t)r * D_DIM + lane * 4;
  float4 a = *(const float4*)(hi + off);
  float4 b = *(const float4*)(hj + off);

  bf16x4 oa, ob;
  oa[0] = (bf16_t)(a.x * SQRT2); oa[1] = (bf16_t)(a.y * SQRT2);
  oa[2] = (bf16_t)(a.z * SQRT2); oa[3] = (bf16_t)(a.w * SQRT2);
  ob[0] = (bf16_t)(b.x * SQRT2); ob[1] = (bf16_t)(b.y * SQRT2);
  ob[2] = (bf16_t)(b.z * SQRT2); ob[3] = (bf16_t)(b.w * SQRT2);
  // lane holds cols lane*4..+3 = plane (lane>>1), chunk-half (lane&1)
  const int plane = lane >> 1;
  const int halfo = (lane & 1) * 4;
  *(bf16x4*)(hbP + ((size_t)plane * PLANE + r) * 8 + halfo) = oa;
  *(bf16x4*)(hbP + ((size_t)plane * PLANE + BATCH + r) * 8 + halfo) = ob;

  float d = a.x * b.x + a.y * b.y + a.z * b.z + a.w * b.w;
#pragma unroll
  for (int o = 32; o >= 1; o >>= 1) d += __shfl_xor(d, o);
  __shared__ float ps[4];
  if (lane == 0) ps[wave] = d;
  // zero 8 Zrow entries per block (8192 total over 1024 blocks)
  if (threadIdx.x < 8) Zrow[blockIdx.x * 8 + threadIdx.x] = 0.f;
  __syncthreads();
  if (threadIdx.x == 0) posPartial[blockIdx.x] = ps[0] + ps[1] + ps[2] + ps[3];
}

// Upper-triangular 64x64 WAVE-tiles of sim = h.h^T; fused exp(sim-SHIFT) with
// row/col sum accumulation into Zrow. 2064 blocks x 4 waves = 8256 tiles.
// NO LDS. NO BARRIERS. Rounds 0-9 showed every barrier-lockstepped LDS-staging
// variant floors at 38-60us (sync overhead, not bandwidth). Here each wave
// streams its fragments DIRECTLY from the L2-resident packed array (coalesced
// by construction), depth-2 register prefetch with counted vmcnt + sched
// fences (r6-verified discipline). Floors: L2 528MB ~15us, MFMA ~7us.
__global__ __launch_bounds__(256, 3) void k_gemm(const bf16_t* __restrict__ hbP,
                                                 float* __restrict__ Zrow) {
  const int lane = threadIdx.x & 63;
  const int wave = threadIdx.x >> 6;
  const int t = blockIdx.x * 4 + wave;  // 0..8255
  // decode linear tile id -> (bi <= bj) triangular pair, 64-granular
  int bj = (int)((sqrtf(8.0f * (float)t + 1.0f) - 1.0f) * 0.5f);
  while ((bj + 1) * (bj + 2) / 2 <= t) ++bj;
  while (bj * (bj + 1) / 2 > t) --bj;
  const int bi = t - bj * (bj + 1) / 2;
  const int rBase = bi * 64;
  const int cBase = bj * 64;
  const bool diag = (bi == bj);

  const int quad = lane >> 4, l16 = lane & 15;

  // fragment base: plane = ks*4 + quad, row = base + mt*16 + l16
  // element addr = (plane*8192 + row)*8 ; slab step = 4 planes = 262144 elems
  const bf16_t* aP = hbP + ((size_t)quad * PLANE + rBase + l16) * 8;
  const bf16_t* bP = hbP + ((size_t)quad * PLANE + cBase + l16) * 8;

  f32x4 acc[4][4];
#pragma unroll
  for (int i = 0; i < 4; ++i)
#pragma unroll
    for (int j = 0; j < 4; ++j) acc[i][j] = (f32x4){0.f, 0.f, 0.f, 0.f};

  auto LOADS = [&](bf16x8 A[4], bf16x8 B[4], int ks) {
#pragma unroll
    for (int mt = 0; mt < 4; ++mt)
      A[mt] = *(const bf16x8*)(aP + (size_t)ks * (4 * PLANE * 8) + mt * 128);
#pragma unroll
    for (int nt = 0; nt < 4; ++nt)
      B[nt] = *(const bf16x8*)(bP + (size_t)ks * (4 * PLANE * 8) + nt * 128);
  };
  auto MM = [&](const bf16x8 A[4], const bf16x8 B[4]) {
#pragma unroll
    for (int mt = 0; mt < 4; ++mt)
#pragma unroll
      for (int nt = 0; nt < 4; ++nt)
        acc[mt][nt] = __builtin_amdgcn_mfma_f32_16x16x32_bf16(A[mt], B[nt],
                                                              acc[mt][nt], 0, 0, 0);
  };

  // depth-2 register pipeline: sets X,Y; 8 outstanding loads per set.
  // At each VMCNT(8): current set's 8 landed, next set's 8 still in flight.
  bf16x8 aX[4], bX[4], aY[4], bY[4];
  LOADS(aX, bX, 0);
  LOADS(aY, bY, 1);
  VMCNT(8); SCHED_FENCE(); MM(aX, bX); LOADS(aX, bX, 2);  // k=0
  VMCNT(8); SCHED_FENCE(); MM(aY, bY); LOADS(aY, bY, 3);  // k=1
  VMCNT(8); SCHED_FENCE(); MM(aX, bX); LOADS(aX, bX, 4);  // k=2
  VMCNT(8); SCHED_FENCE(); MM(aY, bY); LOADS(aY, bY, 5);  // k=3
  VMCNT(8); SCHED_FENCE(); MM(aX, bX); LOADS(aX, bX, 6);  // k=4
  VMCNT(8); SCHED_FENCE(); MM(aY, bY); LOADS(aY, bY, 7);  // k=5
  VMCNT(8); SCHED_FENCE(); MM(aX, bX);                    // k=6
  VMCNT(0); SCHED_FENCE(); MM(aY, bY);                    // k=7

  // epilogue (r0-verified geometry, tile=64x64): e = exp(sim - SHIFT);
  // row sums always, col sums for off-diag (symmetry).
  const int rW = rBase + quad * 4;
  const int cW = cBase + l16;
  float colAcc[4] = {0.f, 0.f, 0.f, 0.f};
#pragma unroll
  for (int mt = 0; mt < 4; ++mt) {
#pragma unroll
    for (int rg = 0; rg < 4; ++rg) {
      const int rr = rW + mt * 16 + rg;
      float s = 0.f;
#pragma unroll
      for (int nt = 0; nt < 4; ++nt) {
        float e = __expf(acc[mt][nt][rg] - SHIFT);
        if (diag && (rr == cW + nt * 16)) e = 0.f;  // mask self-similarity
        s += e;
        colAcc[nt] += e;
      }
      s += __shfl_xor(s, 1);
      s += __shfl_xor(s, 2);
      s += __shfl_xor(s, 4);
      s += __shfl_xor(s, 8);
      if (l16 == 0) atomicAdd(&Zrow[rr], s);
    }
  }
  if (!diag) {
#pragma unroll
    for (int nt = 0; nt < 4; ++nt) {
      float c = colAcc[nt];
      c += __shfl_xor(c, 16);
      c += __shfl_xor(c, 32);
      if (lane < 16) atomicAdd(&Zrow[cW + nt * 16], c);
    }
  }
}

// One block: loss = mean(log Z + SHIFT) - sum(dot)/2048
__global__ void k_finish(const float* __restrict__ Zrow,
                         const float* __restrict__ posPartial,
                         float* __restrict__ out) {
  const int t = threadIdx.x;  // 0..1023
  float4 z0 = *(const float4*)(Zrow + t * 8);
  float4 z1 = *(const float4*)(Zrow + t * 8 + 4);
  float sl = __logf(z0.x) + __logf(z0.y) + __logf(z0.z) + __logf(z0.w) +
             __logf(z1.x) + __logf(z1.y) + __logf(z1.z) + __logf(z1.w);
  float sp = posPartial[t];
#pragma unroll
  for (int o = 32; o >= 1; o >>= 1) {
    sl += __shfl_xor(sl, o);
    sp += __shfl_xor(sp, o);
  }
  __shared__ float pl[16], pp[16];
  const int wave = t >> 6, lane = t & 63;
  if (lane == 0) { pl[wave] = sl; pp[wave] = sp; }
  __syncthreads();
  if (t == 0) {
    float L = 0.f, P = 0.f;
    for (int i = 0; i < 16; ++i) { L += pl[i]; P += pp[i]; }
    out[0] = L / (float)N_TOT + SHIFT - P / 2048.0f;
  }
}

extern "C" void kernel_launch(void* const* d_in, const int* in_sizes, int n_in,
                              void* d_out, int out_size, void* d_ws, size_t ws_size,
                              hipStream_t stream) {
  const float* hi = (const float*)d_in[0];
  const float* hj = (const float*)d_in[1];
  float* out = (float*)d_out;

  bf16_t* hbP = (bf16_t*)d_ws;                                       // 4 MB packed
  float* Zrow = (float*)((char*)d_ws + (size_t)N_TOT * D_DIM * 2);   // 32 KB
  float* posPartial = Zrow + N_TOT;                                  // 4 KB

  k_prep<<<1024, 256, 0, stream>>>(hi, hj, hbP, Zrow, posPartial);
  k_gemm<<<NWTILE / 4, 256, 0, stream>>>(hbP, Zrow);
  k_finish<<<1, 1024, 0, stream>>>(Zrow, posPartial, out);
}